// Round 6
// baseline (515.472 us; speedup 1.0000x reference)
//
#include <hip/hip_runtime.h>
#include <hip/hip_bf16.h>
#include <cstdint>

#define B_  4096
#define T_  20
#define F_  32
#define E_  128
#define H_  2
#define D_  64
#define L_  3
#define HD_ 128
#define EPS_ 1e-5f

typedef __bf16 bfv8 __attribute__((ext_vector_type(8)));
typedef __bf16 bfv4 __attribute__((ext_vector_type(4)));
typedef float  f32x4 __attribute__((ext_vector_type(4)));

__device__ __forceinline__ f32x4 mfma16(bfv8 a, bfv8 b, f32x4 c) {
    return __builtin_amdgcn_mfma_f32_16x16x32_bf16(a, b, c, 0, 0, 0);
}

__device__ __forceinline__ void gload16(const __bf16* g, __bf16* l) {
    __builtin_amdgcn_global_load_lds(
        (const __attribute__((address_space(1))) void*)(g),
        (__attribute__((address_space(3))) void*)(l),
        16, 0, 0);
}

// ---------------------------------------------------------------------------
// 0a. pack attention weights into MFMA-fragment-ready bf16
// ---------------------------------------------------------------------------
__global__ __launch_bounds__(256) void pack_weights_kernel(
    const float* __restrict__ Wq, const float* __restrict__ Wk,
    const float* __restrict__ Wv, const float* __restrict__ Wres,
    __bf16* __restrict__ out)
{
    int mi = blockIdx.x;   // l*4 + p
    int tile = blockIdx.y; // 0..7
    int l = mi >> 2, p = mi & 3;
    const float* Wb = (p == 0 ? Wq : p == 1 ? Wk : p == 2 ? Wv : Wres) + l * 16384;
    int tid = threadIdx.x;
    int ks = tid >> 6, lane = tid & 63;
    int l15 = lane & 15, lgg = lane >> 4;
    const float* src = Wb + (ks * 32 + lgg * 8) * HD_ + tile * 16 + l15;
    __bf16* dst = out + (int64_t)mi * 16384 + ((tile * 4 + ks) * 64 + lane) * 8;
    #pragma unroll
    for (int t = 0; t < 8; t++) dst[t] = (__bf16)src[t * HD_];
}

// ---------------------------------------------------------------------------
// 0b. transpose-pack f32 [K][N] -> bf16 [N][K]
// ---------------------------------------------------------------------------
__global__ __launch_bounds__(256) void transpose_pack_kernel(
    const float* __restrict__ in, __bf16* __restrict__ out, int K, int N)
{
    __shared__ float t[64][65];
    int k0 = blockIdx.x * 64, n0 = blockIdx.y * 64;
    int r = threadIdx.x >> 4, c = (threadIdx.x & 15) * 4;
    for (int rr = r; rr < 64; rr += 16) {
        float4 v = *(const float4*)&in[(int64_t)(k0 + rr) * N + n0 + c];
        t[rr][c] = v.x; t[rr][c + 1] = v.y; t[rr][c + 2] = v.z; t[rr][c + 3] = v.w;
    }
    __syncthreads();
    for (int rr = r; rr < 64; rr += 16) {
        bfv4 o;
        o[0] = (__bf16)t[c + 0][rr];
        o[1] = (__bf16)t[c + 1][rr];
        o[2] = (__bf16)t[c + 2][rr];
        o[3] = (__bf16)t[c + 3][rr];
        *(bfv4*)&out[(int64_t)(n0 + rr) * K + k0 + c] = o;
    }
}

// ---------------------------------------------------------------------------
// 1. token embedding -> bf16 emb row (field 0)
// ---------------------------------------------------------------------------
__global__ __launch_bounds__(128) void tok_embed_kernel(
    const int* __restrict__ tokens, const float* __restrict__ word_emb,
    const float* __restrict__ W_tok, __bf16* __restrict__ embbf)
{
    int b = blockIdx.x;
    int tid = threadIdx.x;
    __shared__ float m[300];
    float a0 = 0.f, a1 = 0.f, a2 = 0.f;
    const int* tb = tokens + b * T_;
    for (int t = 0; t < T_; t++) {
        const float* row = word_emb + (int64_t)tb[t] * 300;
        a0 += row[tid];
        a1 += row[tid + 128];
        if (tid < 44) a2 += row[tid + 256];
    }
    m[tid]       = a0 * (1.f / T_);
    m[tid + 128] = a1 * (1.f / T_);
    if (tid < 44) m[tid + 256] = a2 * (1.f / T_);
    __syncthreads();
    float s = 0.f;
    for (int e = 0; e < 300; e++) s = fmaf(m[e], W_tok[e * E_ + tid], s);
    embbf[(int64_t)b * (F_ * E_) + tid] = (__bf16)s;
}

// ---------------------------------------------------------------------------
// 2. field embedding gather -> bf16
// ---------------------------------------------------------------------------
__global__ __launch_bounds__(256) void field_gather_kernel(
    const int* __restrict__ field_ids, const float* __restrict__ field_tables,
    __bf16* __restrict__ embbf)
{
    int64_t idx = (int64_t)blockIdx.x * blockDim.x + threadIdx.x;
    if (idx >= (int64_t)B_ * 31 * 32) return;
    int c = (int)(idx & 31);
    int64_t tmp = idx >> 5;
    int f = (int)(tmp % 31);
    int b = (int)(tmp / 31);
    int id = field_ids[b * 31 + f];
    const float4* src = (const float4*)field_tables;
    float4 val = src[(int64_t)(f * 1000 + id) * 32 + c];
    bfv4 o;
    o[0] = (__bf16)val.x; o[1] = (__bf16)val.y;
    o[2] = (__bf16)val.z; o[3] = (__bf16)val.w;
    *(bfv4*)&embbf[(int64_t)b * 4096 + (1 + f) * 128 + c * 4] = o;
}

// ---------------------------------------------------------------------------
// 3. bf16 MFMA GEMM, B^T operand. BK=64, BM=128, BN=64, 4 waves.
//    EPI 0: y = relu(bn(acc));  EPI 1: y = acc + bias.
//    OUTBF 1: bf16 out; 0: f32 out.
// ---------------------------------------------------------------------------
template <int OUTBF, int EPI>
__global__ __launch_bounds__(256) void gemm_bt_bf16(
    const __bf16* __restrict__ A, const __bf16* __restrict__ Bt,
    void* __restrict__ Cout, int M, int N, int K,
    const float* __restrict__ gp, const float* __restrict__ bp,
    const float* __restrict__ mp, const float* __restrict__ vp)
{
    __shared__ __bf16 As[128 * 64];   // 16 KB
    __shared__ __bf16 Bs[64 * 64];    // 8 KB
    const int tid = threadIdx.x;
    const int wid = tid >> 6, lane = tid & 63;
    const int l15 = lane & 15, lg = lane >> 4;
    const int wr = wid >> 1, wc = wid & 1;
    const int bm = blockIdx.x, bn = blockIdx.y;

    const int srow = lane >> 3, sp = lane & 7;
    const __bf16* Ag[4]; const __bf16* Bg[2];
    __bf16* Ad[4]; __bf16* Bd[2];
    #pragma unroll
    for (int ga = 0; ga < 4; ga++) {
        int row = wid * 32 + ga * 8 + srow;
        int slot = sp ^ (row & 7);
        Ag[ga] = A + (int64_t)(bm * 128 + row) * K + slot * 8;
        Ad[ga] = &As[(wid * 32 + ga * 8) * 64];
    }
    #pragma unroll
    for (int gb = 0; gb < 2; gb++) {
        int row = wid * 16 + gb * 8 + srow;
        int slot = sp ^ (row & 7);
        Bg[gb] = Bt + (int64_t)(bn * 64 + row) * K + slot * 8;
        Bd[gb] = &Bs[(wid * 16 + gb * 8) * 64];
    }

    int ar[2][4], br2[2][2];
    #pragma unroll
    for (int ks = 0; ks < 2; ks++) {
        #pragma unroll
        for (int mi = 0; mi < 4; mi++) {
            int row = wr * 64 + mi * 16 + l15;
            ar[ks][mi] = row * 64 + (((ks * 4 + lg) ^ (row & 7)) * 8);
        }
        #pragma unroll
        for (int ni = 0; ni < 2; ni++) {
            int row = wc * 32 + ni * 16 + l15;
            br2[ks][ni] = row * 64 + (((ks * 4 + lg) ^ (row & 7)) * 8);
        }
    }

    f32x4 acc[4][2];
    #pragma unroll
    for (int mi = 0; mi < 4; mi++)
        #pragma unroll
        for (int ni = 0; ni < 2; ni++) acc[mi][ni] = (f32x4){0.f, 0.f, 0.f, 0.f};

    for (int k0 = 0; k0 < K; k0 += 64) {
        #pragma unroll
        for (int ga = 0; ga < 4; ga++) gload16(Ag[ga] + k0, Ad[ga]);
        #pragma unroll
        for (int gb = 0; gb < 2; gb++) gload16(Bg[gb] + k0, Bd[gb]);
        __syncthreads();
        #pragma unroll
        for (int ks = 0; ks < 2; ks++) {
            bfv8 af[4], bf2[2];
            #pragma unroll
            for (int mi = 0; mi < 4; mi++) af[mi] = *(const bfv8*)&As[ar[ks][mi]];
            #pragma unroll
            for (int ni = 0; ni < 2; ni++) bf2[ni] = *(const bfv8*)&Bs[br2[ks][ni]];
            #pragma unroll
            for (int mi = 0; mi < 4; mi++)
                #pragma unroll
                for (int ni = 0; ni < 2; ni++)
                    acc[mi][ni] = mfma16(af[mi], bf2[ni], acc[mi][ni]);
        }
        __syncthreads();
    }

    float inv[2], sh[2];
    #pragma unroll
    for (int ni = 0; ni < 2; ni++) {
        int col = bn * 64 + wc * 32 + ni * 16 + l15;
        if constexpr (EPI == 0) {
            float iv = rsqrtf(vp[col] + EPS_) * gp[col];
            inv[ni] = iv;
            sh[ni] = bp[col] - mp[col] * iv;
        } else {
            inv[ni] = 1.f;
            sh[ni] = bp[col];
        }
    }
    #pragma unroll
    for (int mi = 0; mi < 4; mi++)
        #pragma unroll
        for (int ni = 0; ni < 2; ni++) {
            int col = bn * 64 + wc * 32 + ni * 16 + l15;
            #pragma unroll
            for (int r = 0; r < 4; r++) {
                int row = bm * 128 + wr * 64 + mi * 16 + lg * 4 + r;
                float y = fmaf(acc[mi][ni][r], inv[ni], sh[ni]);
                if constexpr (EPI == 0) y = fmaxf(y, 0.f);
                if constexpr (OUTBF)
                    ((__bf16*)Cout)[(int64_t)row * N + col] = (__bf16)y;
                else
                    ((float*)Cout)[(int64_t)row * N + col] = y;
            }
        }
}

// ---------------------------------------------------------------------------
// 4. FUSED 3-layer attention + head, 2 rows/block, 512 threads, 8 waves.
//    Projection: 24 tile-columns (q:0-7, k:8-15, v:16-23); wave handles
//    cols wid*3..+2 over 4 x-tiles (2 rows x 2 field-halves) = 48 MFMA.
//    Residual: each attention wave computes its OWN 16x64 res slice in
//    registers (16 MFMA) -- no r_lds, bit-identical accumulation.
//    LDS 73 KB -> 2 blocks/CU.
// ---------------------------------------------------------------------------
__global__ __launch_bounds__(512, 4) void attn3_head_kernel(
    const __bf16* __restrict__ embbf, const __bf16* __restrict__ pkw,
    const float* __restrict__ lng, const float* __restrict__ lnb,
    const float* __restrict__ h3, const float* __restrict__ Wl,
    const float* __restrict__ bl, float* __restrict__ out)
{
    __shared__ __bf16 xs[2][32 * 128];     // 16 KB, swizzled
    __shared__ __bf16 q_lds[2][32 * 128];  // 16 KB
    __shared__ __bf16 k_lds[2][32 * 128];  // 16 KB
    __shared__ __bf16 vt_lds[2][128 * 32]; // 16 KB
    __shared__ __bf16 p_lds[8 * 512];      // 8 KB (overlaid by red[512] f32)
    __shared__ float  part[2][128];        // 1 KB

    const int tid = threadIdx.x;
    const int wid = tid >> 6, lane = tid & 63;
    const int l15 = lane & 15, lg = lane >> 4;
    const int arow = wid >> 2, h = (wid >> 1) & 1, qh = wid & 1; // attn role
    const int q = qh * 16 + l15;

    // ---- stage x for both rows into swizzled xs
    {
        const __bf16* src = embbf + (int64_t)blockIdx.x * 8192;
        #pragma unroll
        for (int u = 0; u < 2; u++) {
            int c = tid * 2 + u;                 // 0..1023 chunks of 8 bf16
            int brow = c >> 9, fld = (c >> 4) & 31, slot = c & 15;
            bfv8 v = *(const bfv8*)&src[brow * 4096 + fld * 128 + slot * 8];
            *(bfv8*)&xs[brow][fld * 128 + ((slot * 8) ^ ((fld & 7) << 3))] = v;
        }
    }
    __syncthreads();

    float head_partial = 0.f;

    for (int l = 0; l < L_; l++) {
        // ---- x fragments: i = brow*2 + fieldhalf
        bfv8 xf[4][4];
        #pragma unroll
        for (int i = 0; i < 4; i++)
            #pragma unroll
            for (int ks = 0; ks < 4; ks++) {
                int br = i >> 1, fld = (i & 1) * 16 + l15;
                xf[i][ks] = *(const bfv8*)&xs[br][fld * 128 + ((ks * 32 + lg * 8) ^ ((fld & 7) << 3))];
            }

        // ---- q/k/v projection: 3 columns per wave, 4 i-tiles, 4 ks = 48 MFMA
        f32x4 pacc[3][4];
        #pragma unroll
        for (int cc = 0; cc < 3; cc++)
            #pragma unroll
            for (int i = 0; i < 4; i++) pacc[cc][i] = (f32x4){0.f, 0.f, 0.f, 0.f};

        #pragma unroll
        for (int cc = 0; cc < 3; cc++) {
            int col = wid * 3 + cc;
            int mat = col >> 3, m = col & 7;
            const __bf16* W = pkw + (l * 4 + mat) * 16384;
            bfv8 wf[4];
            #pragma unroll
            for (int ks = 0; ks < 4; ks++)
                wf[ks] = *(const bfv8*)(W + ((m * 4 + ks) * 64 + lane) * 8);
            if (mat == 2) {
                #pragma unroll
                for (int i = 0; i < 4; i++)
                    #pragma unroll
                    for (int ks = 0; ks < 4; ks++)
                        pacc[cc][i] = mfma16(xf[i][ks], wf[ks], pacc[cc][i]);
            } else {
                #pragma unroll
                for (int i = 0; i < 4; i++)
                    #pragma unroll
                    for (int ks = 0; ks < 4; ks++)
                        pacc[cc][i] = mfma16(wf[ks], xf[i][ks], pacc[cc][i]);
            }
        }

        // ---- store q/k/v columns to LDS
        #pragma unroll
        for (int cc = 0; cc < 3; cc++) {
            int col = wid * 3 + cc;
            int mat = col >> 3, m = col & 7;
            if (mat == 0) {
                #pragma unroll
                for (int i = 0; i < 4; i++) {
                    int br = i >> 1, fld = (i & 1) * 16 + l15;
                    int j = m * 16 + lg * 4;
                    bfv4 v4;
                    #pragma unroll
                    for (int r = 0; r < 4; r++) v4[r] = (__bf16)(pacc[cc][i][r] * 0.125f);
                    *(bfv4*)&q_lds[br][fld * 128 + (j ^ ((fld & 7) << 3))] = v4;
                }
            } else if (mat == 1) {
                #pragma unroll
                for (int i = 0; i < 4; i++) {
                    int br = i >> 1, fld = (i & 1) * 16 + l15;
                    int j = m * 16 + lg * 4;
                    bfv4 v4;
                    #pragma unroll
                    for (int r = 0; r < 4; r++) v4[r] = (__bf16)pacc[cc][i][r];
                    *(bfv4*)&k_lds[br][fld * 128 + (j ^ ((fld & 7) << 3))] = v4;
                }
            } else {
                #pragma unroll
                for (int i = 0; i < 4; i++) {
                    int br = i >> 1;
                    int d = m * 16 + l15;
                    int key = (i & 1) * 16 + lg * 4;
                    bfv4 v4;
                    #pragma unroll
                    for (int r = 0; r < 4; r++) v4[r] = (__bf16)pacc[cc][i][r];
                    *(bfv4*)&vt_lds[br][d * 32 + (key ^ (((d >> 1) & 3) << 3))] = v4;
                }
            }
        }

        // ---- own residual slice in registers: res[q][h*64+dm*16+lg*4+r]
        f32x4 macc[4];
        {
            const __bf16* Wr = pkw + (l * 4 + 3) * 16384;
            const int ir = arow * 2 + qh;
            #pragma unroll
            for (int dm = 0; dm < 4; dm++) {
                macc[dm] = (f32x4){0.f, 0.f, 0.f, 0.f};
                int m = h * 4 + dm;
                #pragma unroll
                for (int ks = 0; ks < 4; ks++) {
                    bfv8 wf = *(const bfv8*)(Wr + ((m * 4 + ks) * 64 + lane) * 8);
                    macc[dm] = mfma16(wf, xf[ir][ks], macc[dm]);
                }
            }
        }
        __syncthreads();

        // ---- scores S^T = k @ q^T for (arow, h, qh)
        f32x4 sc2[2] = {(f32x4){0.f, 0.f, 0.f, 0.f}, (f32x4){0.f, 0.f, 0.f, 0.f}};
        #pragma unroll
        for (int ks = 0; ks < 2; ks++) {
            int d = h * 64 + ks * 32 + lg * 8;
            bfv8 qb = *(const bfv8*)&q_lds[arow][q * 128 + (d ^ ((q & 7) << 3))];
            #pragma unroll
            for (int km = 0; km < 2; km++) {
                int key = km * 16 + l15;
                bfv8 kb = *(const bfv8*)&k_lds[arow][key * 128 + (d ^ ((key & 7) << 3))];
                sc2[km] = mfma16(kb, qb, sc2[km]);
            }
        }

        // ---- softmax over 32 keys
        float mx = -1e30f;
        #pragma unroll
        for (int km = 0; km < 2; km++)
            #pragma unroll
            for (int r = 0; r < 4; r++) mx = fmaxf(mx, sc2[km][r]);
        mx = fmaxf(mx, __shfl_xor(mx, 16));
        mx = fmaxf(mx, __shfl_xor(mx, 32));
        float pv[2][4];
        float sum = 0.f;
        #pragma unroll
        for (int km = 0; km < 2; km++)
            #pragma unroll
            for (int r = 0; r < 4; r++) {
                float e = __expf(sc2[km][r] - mx);
                pv[km][r] = e; sum += e;
            }
        sum += __shfl_xor(sum, 16);
        sum += __shfl_xor(sum, 32);
        float inv = 1.f / sum;

        // ---- P^T -> wave-private p_lds
        __bf16* pw = p_lds + wid * 512;
        #pragma unroll
        for (int km = 0; km < 2; km++) {
            int key = km * 16 + lg * 4;
            bfv4 v4;
            #pragma unroll
            for (int r = 0; r < 4; r++) v4[r] = (__bf16)(pv[km][r] * inv);
            *(bfv4*)&pw[l15 * 32 + (key ^ (((l15 >> 1) & 3) << 3))] = v4;
        }

        // ---- PV: o^T = v^T @ P^T
        bfv8 pb = *(const bfv8*)&pw[l15 * 32 + ((lg * 8) ^ (((l15 >> 1) & 3) << 3))];
        f32x4 o[4];
        #pragma unroll
        for (int dm = 0; dm < 4; dm++) {
            int d = h * 64 + dm * 16 + l15;
            bfv8 va = *(const bfv8*)&vt_lds[arow][d * 32 + ((lg * 8) ^ (((d >> 1) & 3) << 3))];
            o[dm] = mfma16(va, pb, (f32x4){0.f, 0.f, 0.f, 0.f});
        }

        // ---- relu(o + res), partial LN stats
        float yv[4][4];
        float s1 = 0.f, s2 = 0.f;
        #pragma unroll
        for (int dm = 0; dm < 4; dm++) {
            #pragma unroll
            for (int r = 0; r < 4; r++) {
                float v = fmaxf(o[dm][r] + macc[dm][r], 0.f);
                yv[dm][r] = v;
                s1 += v; s2 += v * v;
            }
        }
        s1 += __shfl_xor(s1, 16); s1 += __shfl_xor(s1, 32);
        s2 += __shfl_xor(s2, 16); s2 += __shfl_xor(s2, 32);
        if (lg == 0) { part[arow][q * 4 + h * 2] = s1; part[arow][q * 4 + h * 2 + 1] = s2; }
        __syncthreads();

        // ---- layernorm
        f32x4 pt = *(const f32x4*)&part[arow][q * 4];
        float mean = (pt[0] + pt[2]) * (1.f / 128.f);
        float var  = (pt[1] + pt[3]) * (1.f / 128.f) - mean * mean;
        float rstd = rsqrtf(var + EPS_);
        const float* lgp = lng + l * HD_;
        const float* lbp = lnb + l * HD_;

        if (l < L_ - 1) {
            #pragma unroll
            for (int dm = 0; dm < 4; dm++) {
                int j = h * 64 + dm * 16 + lg * 4;
                float4 g  = *(const float4*)(lgp + j);
                float4 bb = *(const float4*)(lbp + j);
                bfv4 y;
                y[0] = (__bf16)((yv[dm][0] - mean) * rstd * g.x + bb.x);
                y[1] = (__bf16)((yv[dm][1] - mean) * rstd * g.y + bb.y);
                y[2] = (__bf16)((yv[dm][2] - mean) * rstd * g.z + bb.z);
                y[3] = (__bf16)((yv[dm][3] - mean) * rstd * g.w + bb.w);
                *(bfv4*)&xs[arow][q * 128 + (j ^ ((q & 7) << 3))] = y;
            }
            __syncthreads();
        } else {
            #pragma unroll
            for (int dm = 0; dm < 4; dm++) {
                int j = h * 64 + dm * 16 + lg * 4;
                float4 g  = *(const float4*)(lgp + j);
                float4 bb = *(const float4*)(lbp + j);
                float4 w  = *(const float4*)(Wl + q * HD_ + j);
                head_partial = fmaf((yv[dm][0] - mean) * rstd * g.x + bb.x, w.x, head_partial);
                head_partial = fmaf((yv[dm][1] - mean) * rstd * g.y + bb.y, w.y, head_partial);
                head_partial = fmaf((yv[dm][2] - mean) * rstd * g.z + bb.z, w.z, head_partial);
                head_partial = fmaf((yv[dm][3] - mean) * rstd * g.w + bb.w, w.w, head_partial);
            }
        }
    }

    // ---- per-row reduction of head partials (red overlays p_lds)
    float* red = (float*)p_lds;
    red[tid] = head_partial;
    __syncthreads();
    if ((wid & 3) == 0) {
        int br = wid >> 2;
        int base = br * 256;
        float s = red[base + lane] + red[base + 64 + lane]
                + red[base + 128 + lane] + red[base + 192 + lane];
        int64_t b0 = (int64_t)blockIdx.x * 2 + br;
        s += h3[b0 * 128 + lane]      * Wl[4096 + lane];
        s += h3[b0 * 128 + 64 + lane] * Wl[4096 + 64 + lane];
        #pragma unroll
        for (int off = 32; off; off >>= 1) s += __shfl_down(s, off);
        if (lane == 0) out[b0] = 1.f / (1.f + __expf(-(s + bl[0])));
    }
}

// ---------------------------------------------------------------------------
extern "C" void kernel_launch(void* const* d_in, const int* in_sizes, int n_in,
                              void* d_out, int out_size, void* d_ws, size_t ws_size,
                              hipStream_t stream)
{
    const int*   tokens       = (const int*)  d_in[0];
    const int*   field_ids    = (const int*)  d_in[1];
    const float* word_emb     = (const float*)d_in[2];
    const float* W_tok        = (const float*)d_in[3];
    const float* field_tables = (const float*)d_in[4];
    const float* Wq           = (const float*)d_in[5];
    const float* Wk           = (const float*)d_in[6];
    const float* Wv           = (const float*)d_in[7];
    const float* Wres         = (const float*)d_in[8];
    const float* ln_g         = (const float*)d_in[9];
    const float* ln_b         = (const float*)d_in[10];
    const float* dnn_W1       = (const float*)d_in[11];
    const float* bn1_g        = (const float*)d_in[12];
    const float* bn1_b        = (const float*)d_in[13];
    const float* bn1_m        = (const float*)d_in[14];
    const float* bn1_v        = (const float*)d_in[15];
    const float* dnn_W2       = (const float*)d_in[16];
    const float* bn2_g        = (const float*)d_in[17];
    const float* bn2_b        = (const float*)d_in[18];
    const float* bn2_m        = (const float*)d_in[19];
    const float* bn2_v        = (const float*)d_in[20];
    const float* dnn_W3       = (const float*)d_in[21];
    const float* dnn_b3       = (const float*)d_in[22];
    const float* W_last       = (const float*)d_in[23];
    const float* b_last       = (const float*)d_in[24];
    float* out = (float*)d_out;

    const int64_t embN = (int64_t)B_ * F_ * E_;           // 16,777,216
    __bf16* embbf = (__bf16*)d_ws;                         // 32 MB
    float*  h3    = (float*)(embbf + embN);                // 2 MB
    __bf16* pkw   = (__bf16*)(h3 + (int64_t)B_ * 128);     // 384 KB
    __bf16* W1t   = pkw + 12 * 16384;                      // 8 MB
    __bf16* W2t   = W1t + (int64_t)1024 * 4096;            // 1 MB
    __bf16* W3t   = W2t + (int64_t)512 * 1024;             // 128 KB
    __bf16* h1bf  = W3t + (int64_t)128 * 512;              // 8 MB
    __bf16* h2bf  = h1bf + (int64_t)B_ * 1024;             // 4 MB

    // weight packing
    pack_weights_kernel<<<dim3(12, 8), 256, 0, stream>>>(Wq, Wk, Wv, Wres, pkw);
    transpose_pack_kernel<<<dim3(64, 16), 256, 0, stream>>>(dnn_W1, W1t, 4096, 1024);
    transpose_pack_kernel<<<dim3(16, 8), 256, 0, stream>>>(dnn_W2, W2t, 1024, 512);
    transpose_pack_kernel<<<dim3(8, 2), 256, 0, stream>>>(dnn_W3, W3t, 512, 128);

    // embeddings (bf16)
    tok_embed_kernel<<<B_, 128, 0, stream>>>(tokens, word_emb, W_tok, embbf);
    field_gather_kernel<<<(B_ * 31 * 32) / 256, 256, 0, stream>>>(field_ids, field_tables, embbf);

    // DNN tower (all bf16 MFMA)
    gemm_bt_bf16<1, 0><<<dim3(32, 16), 256, 0, stream>>>(
        embbf, W1t, h1bf, B_, 1024, 4096, bn1_g, bn1_b, bn1_m, bn1_v);
    gemm_bt_bf16<1, 0><<<dim3(32, 8), 256, 0, stream>>>(
        h1bf, W2t, h2bf, B_, 512, 1024, bn2_g, bn2_b, bn2_m, bn2_v);
    gemm_bt_bf16<0, 1><<<dim3(32, 2), 256, 0, stream>>>(
        h2bf, W3t, h3, B_, 128, 512, nullptr, dnn_b3, nullptr, nullptr);

    // fused attention stack + head, 2 rows per block
    attn3_head_kernel<<<B_ / 2, 512, 0, stream>>>(
        embbf, pkw, ln_g, ln_b, h3, W_last, b_last, out);
}

// Round 7
// 249.790 us; speedup vs baseline: 2.0636x; 2.0636x over previous
//
#include <hip/hip_runtime.h>
#include <hip/hip_bf16.h>
#include <cstdint>

#define B_  4096
#define T_  20
#define F_  32
#define E_  128
#define H_  2
#define D_  64
#define L_  3
#define HD_ 128
#define EPS_ 1e-5f

typedef __bf16 bfv8 __attribute__((ext_vector_type(8)));
typedef __bf16 bfv4 __attribute__((ext_vector_type(4)));
typedef float  f32x4 __attribute__((ext_vector_type(4)));

__device__ __forceinline__ f32x4 mfma16(bfv8 a, bfv8 b, f32x4 c) {
    return __builtin_amdgcn_mfma_f32_16x16x32_bf16(a, b, c, 0, 0, 0);
}

__device__ __forceinline__ void gload16(const __bf16* g, __bf16* l) {
    __builtin_amdgcn_global_load_lds(
        (const __attribute__((address_space(1))) void*)(g),
        (__attribute__((address_space(3))) void*)(l),
        16, 0, 0);
}

// ---------------------------------------------------------------------------
// 0a. pack attention weights into MFMA-fragment-ready bf16
// ---------------------------------------------------------------------------
__global__ __launch_bounds__(256) void pack_weights_kernel(
    const float* __restrict__ Wq, const float* __restrict__ Wk,
    const float* __restrict__ Wv, const float* __restrict__ Wres,
    __bf16* __restrict__ out)
{
    int mi = blockIdx.x;   // l*4 + p
    int tile = blockIdx.y; // 0..7
    int l = mi >> 2, p = mi & 3;
    const float* Wb = (p == 0 ? Wq : p == 1 ? Wk : p == 2 ? Wv : Wres) + l * 16384;
    int tid = threadIdx.x;
    int ks = tid >> 6, lane = tid & 63;
    int l15 = lane & 15, lgg = lane >> 4;
    const float* src = Wb + (ks * 32 + lgg * 8) * HD_ + tile * 16 + l15;
    __bf16* dst = out + (int64_t)mi * 16384 + ((tile * 4 + ks) * 64 + lane) * 8;
    #pragma unroll
    for (int t = 0; t < 8; t++) dst[t] = (__bf16)src[t * HD_];
}

// ---------------------------------------------------------------------------
// 0b. transpose-pack f32 [K][N] -> bf16 [N][K]
// ---------------------------------------------------------------------------
__global__ __launch_bounds__(256) void transpose_pack_kernel(
    const float* __restrict__ in, __bf16* __restrict__ out, int K, int N)
{
    __shared__ float t[64][65];
    int k0 = blockIdx.x * 64, n0 = blockIdx.y * 64;
    int r = threadIdx.x >> 4, c = (threadIdx.x & 15) * 4;
    for (int rr = r; rr < 64; rr += 16) {
        float4 v = *(const float4*)&in[(int64_t)(k0 + rr) * N + n0 + c];
        t[rr][c] = v.x; t[rr][c + 1] = v.y; t[rr][c + 2] = v.z; t[rr][c + 3] = v.w;
    }
    __syncthreads();
    for (int rr = r; rr < 64; rr += 16) {
        bfv4 o;
        o[0] = (__bf16)t[c + 0][rr];
        o[1] = (__bf16)t[c + 1][rr];
        o[2] = (__bf16)t[c + 2][rr];
        o[3] = (__bf16)t[c + 3][rr];
        *(bfv4*)&out[(int64_t)(n0 + rr) * K + k0 + c] = o;
    }
}

// ---------------------------------------------------------------------------
// 1. token embedding -> bf16 emb row (field 0)
// ---------------------------------------------------------------------------
__global__ __launch_bounds__(128) void tok_embed_kernel(
    const int* __restrict__ tokens, const float* __restrict__ word_emb,
    const float* __restrict__ W_tok, __bf16* __restrict__ embbf)
{
    int b = blockIdx.x;
    int tid = threadIdx.x;
    __shared__ float m[300];
    float a0 = 0.f, a1 = 0.f, a2 = 0.f;
    const int* tb = tokens + b * T_;
    for (int t = 0; t < T_; t++) {
        const float* row = word_emb + (int64_t)tb[t] * 300;
        a0 += row[tid];
        a1 += row[tid + 128];
        if (tid < 44) a2 += row[tid + 256];
    }
    m[tid]       = a0 * (1.f / T_);
    m[tid + 128] = a1 * (1.f / T_);
    if (tid < 44) m[tid + 256] = a2 * (1.f / T_);
    __syncthreads();
    float s = 0.f;
    for (int e = 0; e < 300; e++) s = fmaf(m[e], W_tok[e * E_ + tid], s);
    embbf[(int64_t)b * (F_ * E_) + tid] = (__bf16)s;
}

// ---------------------------------------------------------------------------
// 2. field embedding gather -> bf16
// ---------------------------------------------------------------------------
__global__ __launch_bounds__(256) void field_gather_kernel(
    const int* __restrict__ field_ids, const float* __restrict__ field_tables,
    __bf16* __restrict__ embbf)
{
    int64_t idx = (int64_t)blockIdx.x * blockDim.x + threadIdx.x;
    if (idx >= (int64_t)B_ * 31 * 32) return;
    int c = (int)(idx & 31);
    int64_t tmp = idx >> 5;
    int f = (int)(tmp % 31);
    int b = (int)(tmp / 31);
    int id = field_ids[b * 31 + f];
    const float4* src = (const float4*)field_tables;
    float4 val = src[(int64_t)(f * 1000 + id) * 32 + c];
    bfv4 o;
    o[0] = (__bf16)val.x; o[1] = (__bf16)val.y;
    o[2] = (__bf16)val.z; o[3] = (__bf16)val.w;
    *(bfv4*)&embbf[(int64_t)b * 4096 + (1 + f) * 128 + c * 4] = o;
}

// ---------------------------------------------------------------------------
// 3. bf16 MFMA GEMM, B^T operand. BK=64, BM=128, BN=64, 4 waves.
// ---------------------------------------------------------------------------
template <int OUTBF, int EPI>
__global__ __launch_bounds__(256) void gemm_bt_bf16(
    const __bf16* __restrict__ A, const __bf16* __restrict__ Bt,
    void* __restrict__ Cout, int M, int N, int K,
    const float* __restrict__ gp, const float* __restrict__ bp,
    const float* __restrict__ mp, const float* __restrict__ vp)
{
    __shared__ __bf16 As[128 * 64];   // 16 KB
    __shared__ __bf16 Bs[64 * 64];    // 8 KB
    const int tid = threadIdx.x;
    const int wid = tid >> 6, lane = tid & 63;
    const int l15 = lane & 15, lg = lane >> 4;
    const int wr = wid >> 1, wc = wid & 1;
    const int bm = blockIdx.x, bn = blockIdx.y;

    const int srow = lane >> 3, sp = lane & 7;
    const __bf16* Ag[4]; const __bf16* Bg[2];
    __bf16* Ad[4]; __bf16* Bd[2];
    #pragma unroll
    for (int ga = 0; ga < 4; ga++) {
        int row = wid * 32 + ga * 8 + srow;
        int slot = sp ^ (row & 7);
        Ag[ga] = A + (int64_t)(bm * 128 + row) * K + slot * 8;
        Ad[ga] = &As[(wid * 32 + ga * 8) * 64];
    }
    #pragma unroll
    for (int gb = 0; gb < 2; gb++) {
        int row = wid * 16 + gb * 8 + srow;
        int slot = sp ^ (row & 7);
        Bg[gb] = Bt + (int64_t)(bn * 64 + row) * K + slot * 8;
        Bd[gb] = &Bs[(wid * 16 + gb * 8) * 64];
    }

    int ar[2][4], br2[2][2];
    #pragma unroll
    for (int ks = 0; ks < 2; ks++) {
        #pragma unroll
        for (int mi = 0; mi < 4; mi++) {
            int row = wr * 64 + mi * 16 + l15;
            ar[ks][mi] = row * 64 + (((ks * 4 + lg) ^ (row & 7)) * 8);
        }
        #pragma unroll
        for (int ni = 0; ni < 2; ni++) {
            int row = wc * 32 + ni * 16 + l15;
            br2[ks][ni] = row * 64 + (((ks * 4 + lg) ^ (row & 7)) * 8);
        }
    }

    f32x4 acc[4][2];
    #pragma unroll
    for (int mi = 0; mi < 4; mi++)
        #pragma unroll
        for (int ni = 0; ni < 2; ni++) acc[mi][ni] = (f32x4){0.f, 0.f, 0.f, 0.f};

    for (int k0 = 0; k0 < K; k0 += 64) {
        #pragma unroll
        for (int ga = 0; ga < 4; ga++) gload16(Ag[ga] + k0, Ad[ga]);
        #pragma unroll
        for (int gb = 0; gb < 2; gb++) gload16(Bg[gb] + k0, Bd[gb]);
        __syncthreads();
        #pragma unroll
        for (int ks = 0; ks < 2; ks++) {
            bfv8 af[4], bf2[2];
            #pragma unroll
            for (int mi = 0; mi < 4; mi++) af[mi] = *(const bfv8*)&As[ar[ks][mi]];
            #pragma unroll
            for (int ni = 0; ni < 2; ni++) bf2[ni] = *(const bfv8*)&Bs[br2[ks][ni]];
            #pragma unroll
            for (int mi = 0; mi < 4; mi++)
                #pragma unroll
                for (int ni = 0; ni < 2; ni++)
                    acc[mi][ni] = mfma16(af[mi], bf2[ni], acc[mi][ni]);
        }
        __syncthreads();
    }

    float inv[2], sh[2];
    #pragma unroll
    for (int ni = 0; ni < 2; ni++) {
        int col = bn * 64 + wc * 32 + ni * 16 + l15;
        if constexpr (EPI == 0) {
            float iv = rsqrtf(vp[col] + EPS_) * gp[col];
            inv[ni] = iv;
            sh[ni] = bp[col] - mp[col] * iv;
        } else {
            inv[ni] = 1.f;
            sh[ni] = bp[col];
        }
    }
    #pragma unroll
    for (int mi = 0; mi < 4; mi++)
        #pragma unroll
        for (int ni = 0; ni < 2; ni++) {
            int col = bn * 64 + wc * 32 + ni * 16 + l15;
            #pragma unroll
            for (int r = 0; r < 4; r++) {
                int row = bm * 128 + wr * 64 + mi * 16 + lg * 4 + r;
                float y = fmaf(acc[mi][ni][r], inv[ni], sh[ni]);
                if constexpr (EPI == 0) y = fmaxf(y, 0.f);
                if constexpr (OUTBF)
                    ((__bf16*)Cout)[(int64_t)row * N + col] = (__bf16)y;
                else
                    ((float*)Cout)[(int64_t)row * N + col] = y;
            }
        }
}

// ---------------------------------------------------------------------------
// 4. FUSED 3-layer attention + head, 2 rows/block, 512 threads, 8 waves.
//    Register-budget version: projection one column at a time (pc[4] live),
//    x fragments re-read from LDS on demand (no persistent xf[4][4]).
//    LDS 73 KB -> 2 blocks/CU; live set ~100 VGPR -> fits (512,4) cap.
// ---------------------------------------------------------------------------
__global__ __launch_bounds__(512, 4) void attn3_head_kernel(
    const __bf16* __restrict__ embbf, const __bf16* __restrict__ pkw,
    const float* __restrict__ lng, const float* __restrict__ lnb,
    const float* __restrict__ h3, const float* __restrict__ Wl,
    const float* __restrict__ bl, float* __restrict__ out)
{
    __shared__ __bf16 xs[2][32 * 128];     // 16 KB, swizzled
    __shared__ __bf16 q_lds[2][32 * 128];  // 16 KB
    __shared__ __bf16 k_lds[2][32 * 128];  // 16 KB
    __shared__ __bf16 vt_lds[2][128 * 32]; // 16 KB
    __shared__ __bf16 p_lds[8 * 512];      // 8 KB (overlaid by red[512] f32)
    __shared__ float  part[2][128];        // 1 KB

    const int tid = threadIdx.x;
    const int wid = tid >> 6, lane = tid & 63;
    const int l15 = lane & 15, lg = lane >> 4;
    const int arow = wid >> 2, h = (wid >> 1) & 1, qh = wid & 1; // attn role
    const int q = qh * 16 + l15;

    // ---- stage x for both rows into swizzled xs
    {
        const __bf16* src = embbf + (int64_t)blockIdx.x * 8192;
        #pragma unroll
        for (int u = 0; u < 2; u++) {
            int c = tid * 2 + u;                 // 0..1023 chunks of 8 bf16
            int brow = c >> 9, fld = (c >> 4) & 31, slot = c & 15;
            bfv8 v = *(const bfv8*)&src[brow * 4096 + fld * 128 + slot * 8];
            *(bfv8*)&xs[brow][fld * 128 + ((slot * 8) ^ ((fld & 7) << 3))] = v;
        }
    }
    __syncthreads();

    float head_partial = 0.f;

    for (int l = 0; l < L_; l++) {
        // ---- q/k/v projection: ONE column at a time (minimal live set).
        //      col = wid*3+cc in 0..23; mat = col>>3 (0:q,1:k,2:v), m = col&7.
        #pragma unroll 1
        for (int cc = 0; cc < 3; cc++) {
            const int col = wid * 3 + cc;
            const int mat = col >> 3, m = col & 7;
            const __bf16* W = pkw + (l * 4 + mat) * 16384;
            bfv8 wf[4];
            #pragma unroll
            for (int ks = 0; ks < 4; ks++)
                wf[ks] = *(const bfv8*)(W + ((m * 4 + ks) * 64 + lane) * 8);
            f32x4 pc[4];
            #pragma unroll
            for (int i = 0; i < 4; i++) pc[i] = (f32x4){0.f, 0.f, 0.f, 0.f};

            if (mat == 2) {
                #pragma unroll
                for (int i = 0; i < 4; i++) {
                    int br = i >> 1, fld = (i & 1) * 16 + l15;
                    #pragma unroll
                    for (int ks = 0; ks < 4; ks++) {
                        bfv8 xv = *(const bfv8*)&xs[br][fld * 128 + ((ks * 32 + lg * 8) ^ ((fld & 7) << 3))];
                        pc[i] = mfma16(xv, wf[ks], pc[i]);
                    }
                }
            } else {
                #pragma unroll
                for (int i = 0; i < 4; i++) {
                    int br = i >> 1, fld = (i & 1) * 16 + l15;
                    #pragma unroll
                    for (int ks = 0; ks < 4; ks++) {
                        bfv8 xv = *(const bfv8*)&xs[br][fld * 128 + ((ks * 32 + lg * 8) ^ ((fld & 7) << 3))];
                        pc[i] = mfma16(wf[ks], xv, pc[i]);
                    }
                }
            }

            // store this column
            if (mat == 0) {
                #pragma unroll
                for (int i = 0; i < 4; i++) {
                    int br = i >> 1, fld = (i & 1) * 16 + l15;
                    int j = m * 16 + lg * 4;
                    bfv4 v4;
                    #pragma unroll
                    for (int r = 0; r < 4; r++) v4[r] = (__bf16)(pc[i][r] * 0.125f);
                    *(bfv4*)&q_lds[br][fld * 128 + (j ^ ((fld & 7) << 3))] = v4;
                }
            } else if (mat == 1) {
                #pragma unroll
                for (int i = 0; i < 4; i++) {
                    int br = i >> 1, fld = (i & 1) * 16 + l15;
                    int j = m * 16 + lg * 4;
                    bfv4 v4;
                    #pragma unroll
                    for (int r = 0; r < 4; r++) v4[r] = (__bf16)pc[i][r];
                    *(bfv4*)&k_lds[br][fld * 128 + (j ^ ((fld & 7) << 3))] = v4;
                }
            } else {
                #pragma unroll
                for (int i = 0; i < 4; i++) {
                    int br = i >> 1;
                    int d = m * 16 + l15;
                    int key = (i & 1) * 16 + lg * 4;
                    bfv4 v4;
                    #pragma unroll
                    for (int r = 0; r < 4; r++) v4[r] = (__bf16)pc[i][r];
                    *(bfv4*)&vt_lds[br][d * 32 + (key ^ (((d >> 1) & 3) << 3))] = v4;
                }
            }
        }

        // ---- own residual slice in registers: res rows = (arow, fld=q)
        f32x4 macc[4];
        {
            const __bf16* Wr = pkw + (l * 4 + 3) * 16384;
            bfv8 xr[4];
            #pragma unroll
            for (int ks = 0; ks < 4; ks++)
                xr[ks] = *(const bfv8*)&xs[arow][q * 128 + ((ks * 32 + lg * 8) ^ ((q & 7) << 3))];
            #pragma unroll
            for (int dm = 0; dm < 4; dm++) {
                macc[dm] = (f32x4){0.f, 0.f, 0.f, 0.f};
                int m = h * 4 + dm;
                #pragma unroll
                for (int ks = 0; ks < 4; ks++) {
                    bfv8 wf = *(const bfv8*)(Wr + ((m * 4 + ks) * 64 + lane) * 8);
                    macc[dm] = mfma16(wf, xr[ks], macc[dm]);
                }
            }
        }
        __syncthreads();

        // ---- scores S^T = k @ q^T for (arow, h, qh)
        f32x4 sc2[2] = {(f32x4){0.f, 0.f, 0.f, 0.f}, (f32x4){0.f, 0.f, 0.f, 0.f}};
        #pragma unroll
        for (int ks = 0; ks < 2; ks++) {
            int d = h * 64 + ks * 32 + lg * 8;
            bfv8 qb = *(const bfv8*)&q_lds[arow][q * 128 + (d ^ ((q & 7) << 3))];
            #pragma unroll
            for (int km = 0; km < 2; km++) {
                int key = km * 16 + l15;
                bfv8 kb = *(const bfv8*)&k_lds[arow][key * 128 + (d ^ ((key & 7) << 3))];
                sc2[km] = mfma16(kb, qb, sc2[km]);
            }
        }

        // ---- softmax over 32 keys
        float mx = -1e30f;
        #pragma unroll
        for (int km = 0; km < 2; km++)
            #pragma unroll
            for (int r = 0; r < 4; r++) mx = fmaxf(mx, sc2[km][r]);
        mx = fmaxf(mx, __shfl_xor(mx, 16));
        mx = fmaxf(mx, __shfl_xor(mx, 32));
        float pv[2][4];
        float sum = 0.f;
        #pragma unroll
        for (int km = 0; km < 2; km++)
            #pragma unroll
            for (int r = 0; r < 4; r++) {
                float e = __expf(sc2[km][r] - mx);
                pv[km][r] = e; sum += e;
            }
        sum += __shfl_xor(sum, 16);
        sum += __shfl_xor(sum, 32);
        float inv = 1.f / sum;

        // ---- P^T -> wave-private p_lds
        __bf16* pw = p_lds + wid * 512;
        #pragma unroll
        for (int km = 0; km < 2; km++) {
            int key = km * 16 + lg * 4;
            bfv4 v4;
            #pragma unroll
            for (int r = 0; r < 4; r++) v4[r] = (__bf16)(pv[km][r] * inv);
            *(bfv4*)&pw[l15 * 32 + (key ^ (((l15 >> 1) & 3) << 3))] = v4;
        }

        // ---- PV: o^T = v^T @ P^T
        bfv8 pb = *(const bfv8*)&pw[l15 * 32 + ((lg * 8) ^ (((l15 >> 1) & 3) << 3))];
        f32x4 o[4];
        #pragma unroll
        for (int dm = 0; dm < 4; dm++) {
            int d = h * 64 + dm * 16 + l15;
            bfv8 va = *(const bfv8*)&vt_lds[arow][d * 32 + ((lg * 8) ^ (((d >> 1) & 3) << 3))];
            o[dm] = mfma16(va, pb, (f32x4){0.f, 0.f, 0.f, 0.f});
        }

        // ---- relu(o + res), partial LN stats
        float yv[4][4];
        float s1 = 0.f, s2 = 0.f;
        #pragma unroll
        for (int dm = 0; dm < 4; dm++) {
            #pragma unroll
            for (int r = 0; r < 4; r++) {
                float v = fmaxf(o[dm][r] + macc[dm][r], 0.f);
                yv[dm][r] = v;
                s1 += v; s2 += v * v;
            }
        }
        s1 += __shfl_xor(s1, 16); s1 += __shfl_xor(s1, 32);
        s2 += __shfl_xor(s2, 16); s2 += __shfl_xor(s2, 32);
        if (lg == 0) { part[arow][q * 4 + h * 2] = s1; part[arow][q * 4 + h * 2 + 1] = s2; }
        __syncthreads();

        // ---- layernorm
        f32x4 pt = *(const f32x4*)&part[arow][q * 4];
        float mean = (pt[0] + pt[2]) * (1.f / 128.f);
        float var  = (pt[1] + pt[3]) * (1.f / 128.f) - mean * mean;
        float rstd = rsqrtf(var + EPS_);
        const float* lgp = lng + l * HD_;
        const float* lbp = lnb + l * HD_;

        if (l < L_ - 1) {
            #pragma unroll
            for (int dm = 0; dm < 4; dm++) {
                int j = h * 64 + dm * 16 + lg * 4;
                float4 g  = *(const float4*)(lgp + j);
                float4 bb = *(const float4*)(lbp + j);
                bfv4 y;
                y[0] = (__bf16)((yv[dm][0] - mean) * rstd * g.x + bb.x);
                y[1] = (__bf16)((yv[dm][1] - mean) * rstd * g.y + bb.y);
                y[2] = (__bf16)((yv[dm][2] - mean) * rstd * g.z + bb.z);
                y[3] = (__bf16)((yv[dm][3] - mean) * rstd * g.w + bb.w);
                *(bfv4*)&xs[arow][q * 128 + (j ^ ((q & 7) << 3))] = y;
            }
            __syncthreads();
        } else {
            #pragma unroll
            for (int dm = 0; dm < 4; dm++) {
                int j = h * 64 + dm * 16 + lg * 4;
                float4 g  = *(const float4*)(lgp + j);
                float4 bb = *(const float4*)(lbp + j);
                float4 w  = *(const float4*)(Wl + q * HD_ + j);
                head_partial = fmaf((yv[dm][0] - mean) * rstd * g.x + bb.x, w.x, head_partial);
                head_partial = fmaf((yv[dm][1] - mean) * rstd * g.y + bb.y, w.y, head_partial);
                head_partial = fmaf((yv[dm][2] - mean) * rstd * g.z + bb.z, w.z, head_partial);
                head_partial = fmaf((yv[dm][3] - mean) * rstd * g.w + bb.w, w.w, head_partial);
            }
        }
    }

    // ---- per-row reduction of head partials (red overlays p_lds)
    float* red = (float*)p_lds;
    red[tid] = head_partial;
    __syncthreads();
    if ((wid & 3) == 0) {
        int br = wid >> 2;
        int base = br * 256;
        float s = red[base + lane] + red[base + 64 + lane]
                + red[base + 128 + lane] + red[base + 192 + lane];
        int64_t b0 = (int64_t)blockIdx.x * 2 + br;
        s += h3[b0 * 128 + lane]      * Wl[4096 + lane];
        s += h3[b0 * 128 + 64 + lane] * Wl[4096 + 64 + lane];
        #pragma unroll
        for (int off = 32; off; off >>= 1) s += __shfl_down(s, off);
        if (lane == 0) out[b0] = 1.f / (1.f + __expf(-(s + bl[0])));
    }
}

// ---------------------------------------------------------------------------
extern "C" void kernel_launch(void* const* d_in, const int* in_sizes, int n_in,
                              void* d_out, int out_size, void* d_ws, size_t ws_size,
                              hipStream_t stream)
{
    const int*   tokens       = (const int*)  d_in[0];
    const int*   field_ids    = (const int*)  d_in[1];
    const float* word_emb     = (const float*)d_in[2];
    const float* W_tok        = (const float*)d_in[3];
    const float* field_tables = (const float*)d_in[4];
    const float* Wq           = (const float*)d_in[5];
    const float* Wk           = (const float*)d_in[6];
    const float* Wv           = (const float*)d_in[7];
    const float* Wres         = (const float*)d_in[8];
    const float* ln_g         = (const float*)d_in[9];
    const float* ln_b         = (const float*)d_in[10];
    const float* dnn_W1       = (const float*)d_in[11];
    const float* bn1_g        = (const float*)d_in[12];
    const float* bn1_b        = (const float*)d_in[13];
    const float* bn1_m        = (const float*)d_in[14];
    const float* bn1_v        = (const float*)d_in[15];
    const float* dnn_W2       = (const float*)d_in[16];
    const float* bn2_g        = (const float*)d_in[17];
    const float* bn2_b        = (const float*)d_in[18];
    const float* bn2_m        = (const float*)d_in[19];
    const float* bn2_v        = (const float*)d_in[20];
    const float* dnn_W3       = (const float*)d_in[21];
    const float* dnn_b3       = (const float*)d_in[22];
    const float* W_last       = (const float*)d_in[23];
    const float* b_last       = (const float*)d_in[24];
    float* out = (float*)d_out;

    const int64_t embN = (int64_t)B_ * F_ * E_;           // 16,777,216
    __bf16* embbf = (__bf16*)d_ws;                         // 32 MB
    float*  h3    = (float*)(embbf + embN);                // 2 MB
    __bf16* pkw   = (__bf16*)(h3 + (int64_t)B_ * 128);     // 384 KB
    __bf16* W1t   = pkw + 12 * 16384;                      // 8 MB
    __bf16* W2t   = W1t + (int64_t)1024 * 4096;            // 1 MB
    __bf16* W3t   = W2t + (int64_t)512 * 1024;             // 128 KB
    __bf16* h1bf  = W3t + (int64_t)128 * 512;              // 8 MB
    __bf16* h2bf  = h1bf + (int64_t)B_ * 1024;             // 4 MB

    // weight packing
    pack_weights_kernel<<<dim3(12, 8), 256, 0, stream>>>(Wq, Wk, Wv, Wres, pkw);
    transpose_pack_kernel<<<dim3(64, 16), 256, 0, stream>>>(dnn_W1, W1t, 4096, 1024);
    transpose_pack_kernel<<<dim3(16, 8), 256, 0, stream>>>(dnn_W2, W2t, 1024, 512);
    transpose_pack_kernel<<<dim3(8, 2), 256, 0, stream>>>(dnn_W3, W3t, 512, 128);

    // embeddings (bf16)
    tok_embed_kernel<<<B_, 128, 0, stream>>>(tokens, word_emb, W_tok, embbf);
    field_gather_kernel<<<(B_ * 31 * 32) / 256, 256, 0, stream>>>(field_ids, field_tables, embbf);

    // DNN tower (all bf16 MFMA)
    gemm_bt_bf16<1, 0><<<dim3(32, 16), 256, 0, stream>>>(
        embbf, W1t, h1bf, B_, 1024, 4096, bn1_g, bn1_b, bn1_m, bn1_v);
    gemm_bt_bf16<1, 0><<<dim3(32, 8), 256, 0, stream>>>(
        h1bf, W2t, h2bf, B_, 512, 1024, bn2_g, bn2_b, bn2_m, bn2_v);
    gemm_bt_bf16<0, 1><<<dim3(32, 2), 256, 0, stream>>>(
        h2bf, W3t, h3, B_, 128, 512, nullptr, dnn_b3, nullptr, nullptr);

    // fused attention stack + head, 2 rows per block
    attn3_head_kernel<<<B_ / 2, 512, 0, stream>>>(
        embbf, pkw, ln_g, ln_b, h3, W_last, b_last, out);
}

// Round 8
// 237.683 us; speedup vs baseline: 2.1687x; 1.0509x over previous
//
#include <hip/hip_runtime.h>
#include <hip/hip_bf16.h>
#include <cstdint>

#define B_  4096
#define T_  20
#define F_  32
#define E_  128
#define H_  2
#define D_  64
#define L_  3
#define HD_ 128
#define EPS_ 1e-5f

typedef __bf16 bfv8 __attribute__((ext_vector_type(8)));
typedef __bf16 bfv4 __attribute__((ext_vector_type(4)));
typedef float  f32x4 __attribute__((ext_vector_type(4)));

__device__ __forceinline__ f32x4 mfma16(bfv8 a, bfv8 b, f32x4 c) {
    return __builtin_amdgcn_mfma_f32_16x16x32_bf16(a, b, c, 0, 0, 0);
}

__device__ __forceinline__ void gload16(const __bf16* g, __bf16* l) {
    __builtin_amdgcn_global_load_lds(
        (const __attribute__((address_space(1))) void*)(g),
        (__attribute__((address_space(3))) void*)(l),
        16, 0, 0);
}

// ---------------------------------------------------------------------------
// 0a. pack attention weights into MFMA-fragment-ready bf16
// ---------------------------------------------------------------------------
__global__ __launch_bounds__(256) void pack_weights_kernel(
    const float* __restrict__ Wq, const float* __restrict__ Wk,
    const float* __restrict__ Wv, const float* __restrict__ Wres,
    __bf16* __restrict__ out)
{
    int mi = blockIdx.x;   // l*4 + p
    int tile = blockIdx.y; // 0..7
    int l = mi >> 2, p = mi & 3;
    const float* Wb = (p == 0 ? Wq : p == 1 ? Wk : p == 2 ? Wv : Wres) + l * 16384;
    int tid = threadIdx.x;
    int ks = tid >> 6, lane = tid & 63;
    int l15 = lane & 15, lgg = lane >> 4;
    const float* src = Wb + (ks * 32 + lgg * 8) * HD_ + tile * 16 + l15;
    __bf16* dst = out + (int64_t)mi * 16384 + ((tile * 4 + ks) * 64 + lane) * 8;
    #pragma unroll
    for (int t = 0; t < 8; t++) dst[t] = (__bf16)src[t * HD_];
}

// ---------------------------------------------------------------------------
// 0b. transpose-pack f32 [K][N] -> bf16 [N][K]
// ---------------------------------------------------------------------------
__global__ __launch_bounds__(256) void transpose_pack_kernel(
    const float* __restrict__ in, __bf16* __restrict__ out, int K, int N)
{
    __shared__ float t[64][65];
    int k0 = blockIdx.x * 64, n0 = blockIdx.y * 64;
    int r = threadIdx.x >> 4, c = (threadIdx.x & 15) * 4;
    for (int rr = r; rr < 64; rr += 16) {
        float4 v = *(const float4*)&in[(int64_t)(k0 + rr) * N + n0 + c];
        t[rr][c] = v.x; t[rr][c + 1] = v.y; t[rr][c + 2] = v.z; t[rr][c + 3] = v.w;
    }
    __syncthreads();
    for (int rr = r; rr < 64; rr += 16) {
        bfv4 o;
        o[0] = (__bf16)t[c + 0][rr];
        o[1] = (__bf16)t[c + 1][rr];
        o[2] = (__bf16)t[c + 2][rr];
        o[3] = (__bf16)t[c + 3][rr];
        *(bfv4*)&out[(int64_t)(n0 + rr) * K + k0 + c] = o;
    }
}

// ---------------------------------------------------------------------------
// 1. token embedding -> bf16 emb row (field 0)
// ---------------------------------------------------------------------------
__global__ __launch_bounds__(128) void tok_embed_kernel(
    const int* __restrict__ tokens, const float* __restrict__ word_emb,
    const float* __restrict__ W_tok, __bf16* __restrict__ embbf)
{
    int b = blockIdx.x;
    int tid = threadIdx.x;
    __shared__ float m[300];
    float a0 = 0.f, a1 = 0.f, a2 = 0.f;
    const int* tb = tokens + b * T_;
    for (int t = 0; t < T_; t++) {
        const float* row = word_emb + (int64_t)tb[t] * 300;
        a0 += row[tid];
        a1 += row[tid + 128];
        if (tid < 44) a2 += row[tid + 256];
    }
    m[tid]       = a0 * (1.f / T_);
    m[tid + 128] = a1 * (1.f / T_);
    if (tid < 44) m[tid + 256] = a2 * (1.f / T_);
    __syncthreads();
    float s = 0.f;
    for (int e = 0; e < 300; e++) s = fmaf(m[e], W_tok[e * E_ + tid], s);
    embbf[(int64_t)b * (F_ * E_) + tid] = (__bf16)s;
}

// ---------------------------------------------------------------------------
// 2. field embedding gather -> bf16
// ---------------------------------------------------------------------------
__global__ __launch_bounds__(256) void field_gather_kernel(
    const int* __restrict__ field_ids, const float* __restrict__ field_tables,
    __bf16* __restrict__ embbf)
{
    int64_t idx = (int64_t)blockIdx.x * blockDim.x + threadIdx.x;
    if (idx >= (int64_t)B_ * 31 * 32) return;
    int c = (int)(idx & 31);
    int64_t tmp = idx >> 5;
    int f = (int)(tmp % 31);
    int b = (int)(tmp / 31);
    int id = field_ids[b * 31 + f];
    const float4* src = (const float4*)field_tables;
    float4 val = src[(int64_t)(f * 1000 + id) * 32 + c];
    bfv4 o;
    o[0] = (__bf16)val.x; o[1] = (__bf16)val.y;
    o[2] = (__bf16)val.z; o[3] = (__bf16)val.w;
    *(bfv4*)&embbf[(int64_t)b * 4096 + (1 + f) * 128 + c * 4] = o;
}

// ---------------------------------------------------------------------------
// 3. bf16 MFMA GEMM, B^T operand. BK=64, BM=128, BN=64, 4 waves.
// ---------------------------------------------------------------------------
template <int OUTBF, int EPI>
__global__ __launch_bounds__(256) void gemm_bt_bf16(
    const __bf16* __restrict__ A, const __bf16* __restrict__ Bt,
    void* __restrict__ Cout, int M, int N, int K,
    const float* __restrict__ gp, const float* __restrict__ bp,
    const float* __restrict__ mp, const float* __restrict__ vp)
{
    __shared__ __bf16 As[128 * 64];   // 16 KB
    __shared__ __bf16 Bs[64 * 64];    // 8 KB
    const int tid = threadIdx.x;
    const int wid = tid >> 6, lane = tid & 63;
    const int l15 = lane & 15, lg = lane >> 4;
    const int wr = wid >> 1, wc = wid & 1;
    const int bm = blockIdx.x, bn = blockIdx.y;

    const int srow = lane >> 3, sp = lane & 7;
    const __bf16* Ag[4]; const __bf16* Bg[2];
    __bf16* Ad[4]; __bf16* Bd[2];
    #pragma unroll
    for (int ga = 0; ga < 4; ga++) {
        int row = wid * 32 + ga * 8 + srow;
        int slot = sp ^ (row & 7);
        Ag[ga] = A + (int64_t)(bm * 128 + row) * K + slot * 8;
        Ad[ga] = &As[(wid * 32 + ga * 8) * 64];
    }
    #pragma unroll
    for (int gb = 0; gb < 2; gb++) {
        int row = wid * 16 + gb * 8 + srow;
        int slot = sp ^ (row & 7);
        Bg[gb] = Bt + (int64_t)(bn * 64 + row) * K + slot * 8;
        Bd[gb] = &Bs[(wid * 16 + gb * 8) * 64];
    }

    int ar[2][4], br2[2][2];
    #pragma unroll
    for (int ks = 0; ks < 2; ks++) {
        #pragma unroll
        for (int mi = 0; mi < 4; mi++) {
            int row = wr * 64 + mi * 16 + l15;
            ar[ks][mi] = row * 64 + (((ks * 4 + lg) ^ (row & 7)) * 8);
        }
        #pragma unroll
        for (int ni = 0; ni < 2; ni++) {
            int row = wc * 32 + ni * 16 + l15;
            br2[ks][ni] = row * 64 + (((ks * 4 + lg) ^ (row & 7)) * 8);
        }
    }

    f32x4 acc[4][2];
    #pragma unroll
    for (int mi = 0; mi < 4; mi++)
        #pragma unroll
        for (int ni = 0; ni < 2; ni++) acc[mi][ni] = (f32x4){0.f, 0.f, 0.f, 0.f};

    for (int k0 = 0; k0 < K; k0 += 64) {
        #pragma unroll
        for (int ga = 0; ga < 4; ga++) gload16(Ag[ga] + k0, Ad[ga]);
        #pragma unroll
        for (int gb = 0; gb < 2; gb++) gload16(Bg[gb] + k0, Bd[gb]);
        __syncthreads();
        #pragma unroll
        for (int ks = 0; ks < 2; ks++) {
            bfv8 af[4], bf2[2];
            #pragma unroll
            for (int mi = 0; mi < 4; mi++) af[mi] = *(const bfv8*)&As[ar[ks][mi]];
            #pragma unroll
            for (int ni = 0; ni < 2; ni++) bf2[ni] = *(const bfv8*)&Bs[br2[ks][ni]];
            #pragma unroll
            for (int mi = 0; mi < 4; mi++)
                #pragma unroll
                for (int ni = 0; ni < 2; ni++)
                    acc[mi][ni] = mfma16(af[mi], bf2[ni], acc[mi][ni]);
        }
        __syncthreads();
    }

    float inv[2], sh[2];
    #pragma unroll
    for (int ni = 0; ni < 2; ni++) {
        int col = bn * 64 + wc * 32 + ni * 16 + l15;
        if constexpr (EPI == 0) {
            float iv = rsqrtf(vp[col] + EPS_) * gp[col];
            inv[ni] = iv;
            sh[ni] = bp[col] - mp[col] * iv;
        } else {
            inv[ni] = 1.f;
            sh[ni] = bp[col];
        }
    }
    #pragma unroll
    for (int mi = 0; mi < 4; mi++)
        #pragma unroll
        for (int ni = 0; ni < 2; ni++) {
            int col = bn * 64 + wc * 32 + ni * 16 + l15;
            #pragma unroll
            for (int r = 0; r < 4; r++) {
                int row = bm * 128 + wr * 64 + mi * 16 + lg * 4 + r;
                float y = fmaf(acc[mi][ni][r], inv[ni], sh[ni]);
                if constexpr (EPI == 0) y = fmaxf(y, 0.f);
                if constexpr (OUTBF)
                    ((__bf16*)Cout)[(int64_t)row * N + col] = (__bf16)y;
                else
                    ((float*)Cout)[(int64_t)row * N + col] = y;
            }
        }
}

// ---------------------------------------------------------------------------
// 4. FUSED 3-layer attention + head, 2 rows/block, 512 threads, 8 waves.
//    ALL LDS buffers in MFMA fragment-linear layout [tile][ks][lane][8]:
//    every LDS read is base+lane*16B (zero bank conflicts); writes <=4-way.
//    Res weights staged ONCE per block/layer into dead q/k LDS space via
//    global_load_lds (issued before softmax/PV to hide latency).
//    smem: xs 16K | qf 16K | kf 16K | vtf 16K | pf 8K  = 72 KB -> 2 blk/CU.
// ---------------------------------------------------------------------------
__global__ __launch_bounds__(512, 4) void attn3_head_kernel(
    const __bf16* __restrict__ embbf, const __bf16* __restrict__ pkw,
    const float* __restrict__ lng, const float* __restrict__ lnb,
    const float* __restrict__ h3, const float* __restrict__ Wl,
    const float* __restrict__ bl, float* __restrict__ out)
{
    __shared__ __bf16 smem[8192 * 4 + 4096];
    __shared__ float  part[2][128];
    __bf16* xs  = smem;            // [br][tr][ks][ln][8] : 2*8*64*8
    __bf16* qf  = smem + 8192;     // [br][qtile][dks][ln][8]
    __bf16* kf  = smem + 16384;    // [br][keytile][dks][ln][8]
    __bf16* vtf = smem + 24576;    // [br][dtile(8)][ln][8]
    __bf16* pf  = smem + 32768;    // [wave][ln][8]
    __bf16* wrs = qf;              // Wres staging overlays qf+kf (32 KB)

    const int tid = threadIdx.x;
    const int wid = tid >> 6, lane = tid & 63;
    const int l15 = lane & 15, lg = lane >> 4;
    const int arow = wid >> 2, h = (wid >> 1) & 1, qh = wid & 1;
    const int q = qh * 16 + l15;
    const int half = (lg & 1) * 4;

    // ---- stage x for both rows: fragment-linear, fully conflict-free write
    {
        const __bf16* src = embbf + (int64_t)blockIdx.x * 8192;
        #pragma unroll
        for (int u = 0; u < 2; u++) {
            int g = u * 512 + tid;           // granule index
            int ln = g & 63;
            int fld = (((g >> 8) & 1) << 4) + (ln & 15);
            int e0 = ((g >> 6) & 3) * 32 + (ln >> 4) * 8;
            int br = g >> 9;
            bfv8 v = *(const bfv8*)&src[br * 4096 + fld * 128 + e0];
            *(bfv8*)&xs[g * 8] = v;
        }
    }
    __syncthreads();

    float head_partial = 0.f;

    for (int l = 0; l < L_; l++) {
        // ==== phase 1: q/k/v projection, one column per iteration ====
        #pragma unroll 1
        for (int cc = 0; cc < 3; cc++) {
            const int col = wid * 3 + cc;
            const int mat = col >> 3, m = col & 7;
            const __bf16* W = pkw + (l * 4 + mat) * 16384;
            bfv8 wf[4];
            #pragma unroll
            for (int ks = 0; ks < 4; ks++)
                wf[ks] = *(const bfv8*)(W + ((m * 4 + ks) * 64 + lane) * 8);
            f32x4 pc[4];
            #pragma unroll
            for (int i = 0; i < 4; i++) pc[i] = (f32x4){0.f, 0.f, 0.f, 0.f};

            if (mat == 2) {
                #pragma unroll
                for (int i = 0; i < 4; i++) {
                    int gbase = ((i >> 1) * 8 + (i & 1) * 4) * 64;
                    #pragma unroll
                    for (int ks = 0; ks < 4; ks++) {
                        bfv8 xv = *(const bfv8*)&xs[(gbase + ks * 64 + lane) * 8];
                        pc[i] = mfma16(xv, wf[ks], pc[i]);
                    }
                }
            } else {
                #pragma unroll
                for (int i = 0; i < 4; i++) {
                    int gbase = ((i >> 1) * 8 + (i & 1) * 4) * 64;
                    #pragma unroll
                    for (int ks = 0; ks < 4; ks++) {
                        bfv8 xv = *(const bfv8*)&xs[(gbase + ks * 64 + lane) * 8];
                        pc[i] = mfma16(wf[ks], xv, pc[i]);
                    }
                }
            }

            // store column in fragment-linear layout
            if (mat == 0) {
                const int ln2 = ((((m << 1) + (lg >> 1)) & 3) << 4) + l15;
                #pragma unroll
                for (int i = 0; i < 4; i++) {
                    bfv4 v4;
                    #pragma unroll
                    for (int r = 0; r < 4; r++) v4[r] = (__bf16)(pc[i][r] * 0.125f);
                    int g = ((i >> 1) * 8 + (i & 1) * 4 + (m >> 1)) * 64 + ln2;
                    *(bfv4*)&qf[g * 8 + half] = v4;
                }
            } else if (mat == 1) {
                const int ln2 = ((((m << 1) + (lg >> 1)) & 3) << 4) + l15;
                #pragma unroll
                for (int i = 0; i < 4; i++) {
                    bfv4 v4;
                    #pragma unroll
                    for (int r = 0; r < 4; r++) v4[r] = (__bf16)pc[i][r];
                    int g = ((i >> 1) * 8 + (i & 1) * 4 + (m >> 1)) * 64 + ln2;
                    *(bfv4*)&kf[g * 8 + half] = v4;
                }
            } else {
                #pragma unroll
                for (int i = 0; i < 4; i++) {
                    bfv4 v4;
                    #pragma unroll
                    for (int r = 0; r < 4; r++) v4[r] = (__bf16)pc[i][r];
                    int lnv = ((((i & 1) * 2 + (lg >> 1)) & 3) << 4) + l15;
                    int g = ((i >> 1) * 8 + m) * 64 + lnv;
                    *(bfv4*)&vtf[g * 8 + half] = v4;
                }
            }
        }
        __syncthreads();

        // ==== phase 2: scores S^T = k @ q^T ====
        f32x4 sc2[2] = {(f32x4){0.f, 0.f, 0.f, 0.f}, (f32x4){0.f, 0.f, 0.f, 0.f}};
        #pragma unroll
        for (int ksp = 0; ksp < 2; ksp++) {
            int dks = h * 2 + ksp;
            bfv8 qb = *(const bfv8*)&qf[((arow * 8 + qh * 4 + dks) * 64 + lane) * 8];
            #pragma unroll
            for (int km = 0; km < 2; km++) {
                bfv8 kb = *(const bfv8*)&kf[((arow * 8 + km * 4 + dks) * 64 + lane) * 8];
                sc2[km] = mfma16(kb, qb, sc2[km]);
            }
        }
        __syncthreads();   // q/k now dead -> safe to overwrite with Wres

        // ==== phase 3: issue Wres staging; softmax; P; PV ====
        {
            const __bf16* Wr = pkw + (l * 4 + 3) * 16384;
            #pragma unroll
            for (int c = 0; c < 4; c++) {
                int g = c * 512 + tid;
                gload16(Wr + g * 8, wrs + g * 8);
            }
        }
        float mx = -1e30f;
        #pragma unroll
        for (int km = 0; km < 2; km++)
            #pragma unroll
            for (int r = 0; r < 4; r++) mx = fmaxf(mx, sc2[km][r]);
        mx = fmaxf(mx, __shfl_xor(mx, 16));
        mx = fmaxf(mx, __shfl_xor(mx, 32));
        float pv[2][4];
        float sum = 0.f;
        #pragma unroll
        for (int km = 0; km < 2; km++)
            #pragma unroll
            for (int r = 0; r < 4; r++) {
                float e = __expf(sc2[km][r] - mx);
                pv[km][r] = e; sum += e;
            }
        sum += __shfl_xor(sum, 16);
        sum += __shfl_xor(sum, 32);
        float inv = 1.f / sum;

        __bf16* pw = pf + wid * 512;
        #pragma unroll
        for (int km = 0; km < 2; km++) {
            int ln2 = (((km * 2 + (lg >> 1)) & 3) << 4) + l15;
            bfv4 v4;
            #pragma unroll
            for (int r = 0; r < 4; r++) v4[r] = (__bf16)(pv[km][r] * inv);
            *(bfv4*)&pw[ln2 * 8 + half] = v4;
        }
        bfv8 pb = *(const bfv8*)&pw[lane * 8];
        f32x4 o[4];
        #pragma unroll
        for (int dm = 0; dm < 4; dm++) {
            bfv8 va = *(const bfv8*)&vtf[((arow * 8 + h * 4 + dm) * 64 + lane) * 8];
            o[dm] = mfma16(va, pb, (f32x4){0.f, 0.f, 0.f, 0.f});
        }
        __syncthreads();   // drains vmcnt: staged Wres visible

        // ==== phase 4: res MFMA from shared staged weights ====
        f32x4 macc[4];
        {
            bfv8 xr[4];
            #pragma unroll
            for (int ks = 0; ks < 4; ks++)
                xr[ks] = *(const bfv8*)&xs[((arow * 8 + qh * 4 + ks) * 64 + lane) * 8];
            #pragma unroll
            for (int dm = 0; dm < 4; dm++) {
                macc[dm] = (f32x4){0.f, 0.f, 0.f, 0.f};
                int m = h * 4 + dm;
                #pragma unroll
                for (int ks = 0; ks < 4; ks++) {
                    bfv8 wf = *(const bfv8*)&wrs[((m * 4 + ks) * 64 + lane) * 8];
                    macc[dm] = mfma16(wf, xr[ks], macc[dm]);
                }
            }
        }

        // ---- relu(o + res), partial LN stats
        float yv[4][4];
        float s1 = 0.f, s2 = 0.f;
        #pragma unroll
        for (int dm = 0; dm < 4; dm++) {
            #pragma unroll
            for (int r = 0; r < 4; r++) {
                float v = fmaxf(o[dm][r] + macc[dm][r], 0.f);
                yv[dm][r] = v;
                s1 += v; s2 += v * v;
            }
        }
        s1 += __shfl_xor(s1, 16); s1 += __shfl_xor(s1, 32);
        s2 += __shfl_xor(s2, 16); s2 += __shfl_xor(s2, 32);
        if (lg == 0) { part[arow][q * 4 + h * 2] = s1; part[arow][q * 4 + h * 2 + 1] = s2; }
        __syncthreads();

        // ---- layernorm
        f32x4 pt = *(const f32x4*)&part[arow][q * 4];
        float mean = (pt[0] + pt[2]) * (1.f / 128.f);
        float var  = (pt[1] + pt[3]) * (1.f / 128.f) - mean * mean;
        float rstd = rsqrtf(var + EPS_);
        const float* lgp = lng + l * HD_;
        const float* lbp = lnb + l * HD_;

        if (l < L_ - 1) {
            #pragma unroll
            for (int dm = 0; dm < 4; dm++) {
                int j = h * 64 + dm * 16 + lg * 4;
                float4 g  = *(const float4*)(lgp + j);
                float4 bb = *(const float4*)(lbp + j);
                bfv4 y;
                y[0] = (__bf16)((yv[dm][0] - mean) * rstd * g.x + bb.x);
                y[1] = (__bf16)((yv[dm][1] - mean) * rstd * g.y + bb.y);
                y[2] = (__bf16)((yv[dm][2] - mean) * rstd * g.z + bb.z);
                y[3] = (__bf16)((yv[dm][3] - mean) * rstd * g.w + bb.w);
                int ks2 = h * 2 + (dm >> 1);
                int ln2 = (((dm * 2 + (lg >> 1)) & 3) << 4) + l15;
                int g2 = (arow * 8 + qh * 4 + ks2) * 64 + ln2;
                *(bfv4*)&xs[g2 * 8 + half] = y;
            }
            __syncthreads();
        } else {
            #pragma unroll
            for (int dm = 0; dm < 4; dm++) {
                int j = h * 64 + dm * 16 + lg * 4;
                float4 g  = *(const float4*)(lgp + j);
                float4 bb = *(const float4*)(lbp + j);
                float4 w  = *(const float4*)(Wl + q * HD_ + j);
                head_partial = fmaf((yv[dm][0] - mean) * rstd * g.x + bb.x, w.x, head_partial);
                head_partial = fmaf((yv[dm][1] - mean) * rstd * g.y + bb.y, w.y, head_partial);
                head_partial = fmaf((yv[dm][2] - mean) * rstd * g.z + bb.z, w.z, head_partial);
                head_partial = fmaf((yv[dm][3] - mean) * rstd * g.w + bb.w, w.w, head_partial);
            }
        }
    }

    // ---- per-row reduction of head partials (red overlays pf)
    float* red = (float*)pf;
    red[tid] = head_partial;
    __syncthreads();
    if ((wid & 3) == 0) {
        int br = wid >> 2;
        int base = br * 256;
        float s = red[base + lane] + red[base + 64 + lane]
                + red[base + 128 + lane] + red[base + 192 + lane];
        int64_t b0 = (int64_t)blockIdx.x * 2 + br;
        s += h3[b0 * 128 + lane]      * Wl[4096 + lane];
        s += h3[b0 * 128 + 64 + lane] * Wl[4096 + 64 + lane];
        #pragma unroll
        for (int off = 32; off; off >>= 1) s += __shfl_down(s, off);
        if (lane == 0) out[b0] = 1.f / (1.f + __expf(-(s + bl[0])));
    }
}

// ---------------------------------------------------------------------------
extern "C" void kernel_launch(void* const* d_in, const int* in_sizes, int n_in,
                              void* d_out, int out_size, void* d_ws, size_t ws_size,
                              hipStream_t stream)
{
    const int*   tokens       = (const int*)  d_in[0];
    const int*   field_ids    = (const int*)  d_in[1];
    const float* word_emb     = (const float*)d_in[2];
    const float* W_tok        = (const float*)d_in[3];
    const float* field_tables = (const float*)d_in[4];
    const float* Wq           = (const float*)d_in[5];
    const float* Wk           = (const float*)d_in[6];
    const float* Wv           = (const float*)d_in[7];
    const float* Wres         = (const float*)d_in[8];
    const float* ln_g         = (const float*)d_in[9];
    const float* ln_b         = (const float*)d_in[10];
    const float* dnn_W1       = (const float*)d_in[11];
    const float* bn1_g        = (const float*)d_in[12];
    const float* bn1_b        = (const float*)d_in[13];
    const float* bn1_m        = (const float*)d_in[14];
    const float* bn1_v        = (const float*)d_in[15];
    const float* dnn_W2       = (const float*)d_in[16];
    const float* bn2_g        = (const float*)d_in[17];
    const float* bn2_b        = (const float*)d_in[18];
    const float* bn2_m        = (const float*)d_in[19];
    const float* bn2_v        = (const float*)d_in[20];
    const float* dnn_W3       = (const float*)d_in[21];
    const float* dnn_b3       = (const float*)d_in[22];
    const float* W_last       = (const float*)d_in[23];
    const float* b_last       = (const float*)d_in[24];
    float* out = (float*)d_out;

    const int64_t embN = (int64_t)B_ * F_ * E_;           // 16,777,216
    __bf16* embbf = (__bf16*)d_ws;                         // 32 MB
    float*  h3    = (float*)(embbf + embN);                // 2 MB
    __bf16* pkw   = (__bf16*)(h3 + (int64_t)B_ * 128);     // 384 KB
    __bf16* W1t   = pkw + 12 * 16384;                      // 8 MB
    __bf16* W2t   = W1t + (int64_t)1024 * 4096;            // 1 MB
    __bf16* W3t   = W2t + (int64_t)512 * 1024;             // 128 KB
    __bf16* h1bf  = W3t + (int64_t)128 * 512;              // 8 MB
    __bf16* h2bf  = h1bf + (int64_t)B_ * 1024;             // 4 MB

    // weight packing
    pack_weights_kernel<<<dim3(12, 8), 256, 0, stream>>>(Wq, Wk, Wv, Wres, pkw);
    transpose_pack_kernel<<<dim3(64, 16), 256, 0, stream>>>(dnn_W1, W1t, 4096, 1024);
    transpose_pack_kernel<<<dim3(16, 8), 256, 0, stream>>>(dnn_W2, W2t, 1024, 512);
    transpose_pack_kernel<<<dim3(8, 2), 256, 0, stream>>>(dnn_W3, W3t, 512, 128);

    // embeddings (bf16)
    tok_embed_kernel<<<B_, 128, 0, stream>>>(tokens, word_emb, W_tok, embbf);
    field_gather_kernel<<<(B_ * 31 * 32) / 256, 256, 0, stream>>>(field_ids, field_tables, embbf);

    // DNN tower (all bf16 MFMA)
    gemm_bt_bf16<1, 0><<<dim3(32, 16), 256, 0, stream>>>(
        embbf, W1t, h1bf, B_, 1024, 4096, bn1_g, bn1_b, bn1_m, bn1_v);
    gemm_bt_bf16<1, 0><<<dim3(32, 8), 256, 0, stream>>>(
        h1bf, W2t, h2bf, B_, 512, 1024, bn2_g, bn2_b, bn2_m, bn2_v);
    gemm_bt_bf16<0, 1><<<dim3(32, 2), 256, 0, stream>>>(
        h2bf, W3t, h3, B_, 128, 512, nullptr, dnn_b3, nullptr, nullptr);

    // fused attention stack + head, 2 rows per block
    attn3_head_kernel<<<B_ / 2, 512, 0, stream>>>(
        embbf, pkw, ln_g, ln_b, h3, W_last, b_last, out);
}